// Round 5
// baseline (1593.058 us; speedup 1.0000x reference)
//
#include <hip/hip_runtime.h>
#include <cstdio>

// ---------------------------------------------------------------------------
// GCN 2-layer forward on MI355X.  Round 9: src-slice-resident aggregation.
// Pipeline:
//   1. k_bhist:     histogram of key=(src>>12)*NB+(dst>>8)   (25x391 buckets)
//   2. k_bscan2:    scan 9775 buckets -> bbase[], init gcur[]
//   3. k_partition: edges -> tmp[] packed (src,dst), (slice,dstbucket)-order
//   4. k_bucket:    per-bucket LDS counting sort -> esrc[], off2[s*N+i]
//   5. k_deg:       degree from off2 shards -> dinv[]
//   6. k_castWT:    W -> (Wh,Wl) fp16 split, TRANSPOSED [N][K]
//   7. k_gemm1:     h1 = fp16(x @ W1), 128x256 tile
//   8. k_agg_sl x2: layer-1 aggregation, 128ch per dispatch, src-slice sweep
//   9. k_gemm_mfma: h2 = fp16(h1r @ W2)
//  10. k_agg_sl:    layer-2 aggregation + bias -> out fp32
// Round-9 theory: agg pinned at 3.85 TB/s fabric with ~50% L2 hit because the
// gather table >> 4MiB/XCD L2 (4 null levers: MLP, table size, ordering, gemm).
// Fix: machine-wide src-slice sweep (slice = 4096 rows ~ 1MB/XCD resident),
// dst accumulators in VGPRs across the whole sweep (single generation, all
// 758 blocks co-resident), per-slice CSR so each edge is visited once.
// Predicted: agg1 FETCH 800->~550-650MB sum, dur 230->~150; agg2 372->~260,
// 113->~70; total ~744 -> ~620-650.
// ---------------------------------------------------------------------------

#define NPB 256        // nodes per dst bucket (bucket = dst >> 8)
#define PCHUNK 8192    // edges per partition block
#define SLICE_SHIFT 12 // src slice = src >> 12  (4096 rows)
#define MAXB 12544     // LDS histogram capacity (>= NSLICE*NB = 9775)

typedef _Float16 half2v __attribute__((ext_vector_type(2)));
typedef _Float16 half4v __attribute__((ext_vector_type(4)));
typedef _Float16 half8v __attribute__((ext_vector_type(8)));
typedef float    f32x2  __attribute__((ext_vector_type(2)));
typedef float    f32x4  __attribute__((ext_vector_type(4)));

// 1. bucket histogram over (slice, dstbucket) keys, LDS-privatized
__global__ __launch_bounds__(256) void k_bhist(const int* __restrict__ src,
                                               const int* __restrict__ dst,
                                               int* __restrict__ bcnt,
                                               int e, int nb, int nb2) {
  __shared__ int h[MAXB];
  for (int i = threadIdx.x; i < nb2; i += 256) h[i] = 0;
  __syncthreads();
  int c0 = blockIdx.x * PCHUNK;
  int c1 = min(c0 + PCHUNK, e);
  for (int i = c0 + threadIdx.x; i < c1; i += 256) {
    int key = ((unsigned)src[i] >> SLICE_SHIFT) * nb + ((unsigned)dst[i] >> 8);
    atomicAdd(&h[key], 1);
  }
  __syncthreads();
  for (int i = threadIdx.x; i < nb2; i += 256)
    if (h[i]) atomicAdd(&bcnt[i], h[i]);
}

// 2. single-block scan of nb2 bucket counts -> bbase[0..nb2], gcur init
__global__ __launch_bounds__(512) void k_bscan2(const int* __restrict__ bcnt,
                                                int* __restrict__ bbase,
                                                int* __restrict__ gcur,
                                                int nb2) {
  __shared__ int sm[512];
  const int tid = threadIdx.x;
  const int chunk = (nb2 + 511) >> 9;
  const int c0 = min(tid * chunk, nb2);
  const int c1 = min(c0 + chunk, nb2);
  int sum = 0;
  for (int j = c0; j < c1; ++j) sum += bcnt[j];
  sm[tid] = sum;
  __syncthreads();
  for (int d = 1; d < 512; d <<= 1) {
    int t = (tid >= d) ? sm[tid - d] : 0;
    __syncthreads();
    sm[tid] += t;
    __syncthreads();
  }
  int run = (tid == 0) ? 0 : sm[tid - 1];
  for (int j = c0; j < c1; ++j) {
    bbase[j] = run;
    gcur[j] = run;
    run += bcnt[j];
  }
  if (tid == 511) bbase[nb2] = run;
}

// 3. partition: edges -> tmp[] in (slice, dstbucket)-contiguous runs.
// Single LDS array doubles as count then global cursor.
__global__ __launch_bounds__(256) void k_partition(const int* __restrict__ src,
                                                   const int* __restrict__ dst,
                                                   int* __restrict__ gcur,
                                                   uint2* __restrict__ tmp,
                                                   int e, int nb, int nb2) {
  __shared__ int hist[MAXB];
  for (int i = threadIdx.x; i < nb2; i += 256) hist[i] = 0;
  __syncthreads();
  int c0 = blockIdx.x * PCHUNK;
  int c1 = min(c0 + PCHUNK, e);
  for (int i = c0 + threadIdx.x; i < c1; i += 256) {
    int key = ((unsigned)src[i] >> SLICE_SHIFT) * nb + ((unsigned)dst[i] >> 8);
    atomicAdd(&hist[key], 1);
  }
  __syncthreads();
  for (int i = threadIdx.x; i < nb2; i += 256) {
    int c = hist[i];
    hist[i] = c ? atomicAdd(&gcur[i], c) : 0;  // count -> global cursor
  }
  __syncthreads();
  for (int i = c0 + threadIdx.x; i < c1; i += 256) {
    int s = src[i], d = dst[i];
    int key = ((unsigned)s >> SLICE_SHIFT) * nb + ((unsigned)d >> 8);
    int pos = atomicAdd(&hist[key], 1);
    uint2 v;
    v.x = (unsigned)s;
    v.y = (unsigned)d;
    tmp[pos] = v;
  }
}

// 4. per-(slice,dstbucket) counting sort by dstLocal -> esrc[], off2[s*N+i].
// Shard-contiguity makes off2[s*n+i+1] the correct range end everywhere;
// one global sentinel at off2[NSLICE*n].
__global__ __launch_bounds__(256) void k_bucket(const uint2* __restrict__ tmp,
                                                const int* __restrict__ bbase,
                                                int* __restrict__ off2,
                                                int* __restrict__ esrc, int n) {
  __shared__ int lcnt[NPB];
  __shared__ int lsum[NPB];
  __shared__ int lcur[NPB];
  const int b = blockIdx.y * gridDim.x + blockIdx.x;
  const int tid = threadIdx.x;
  const int r0 = blockIdx.x << 8;
  const int nn = min(NPB, n - r0);
  const int lo = bbase[b], hi = bbase[b + 1];

  lcnt[tid] = 0;
  __syncthreads();
  for (int i = lo + tid; i < hi; i += 256)
    atomicAdd(&lcnt[tmp[i].y & (NPB - 1)], 1);
  __syncthreads();
  lsum[tid] = lcnt[tid];
  __syncthreads();
  for (int d = 1; d < NPB; d <<= 1) {
    int t = (tid >= d) ? lsum[tid - d] : 0;
    __syncthreads();
    lsum[tid] += t;
    __syncthreads();
  }
  int ex = (tid == 0) ? 0 : lsum[tid - 1];
  if (tid < nn) {
    off2[(size_t)blockIdx.y * n + r0 + tid] = lo + ex;
    lcur[tid] = lo + ex;
  }
  if (blockIdx.y == gridDim.y - 1 && r0 + nn == n && tid == 0)
    off2[(size_t)gridDim.y * n] = hi;
  __syncthreads();
  for (int i = lo + tid; i < hi; i += 256) {
    uint2 t2 = tmp[i];
    int pos = atomicAdd(&lcur[t2.y & (NPB - 1)], 1);
    esrc[pos] = (int)t2.x;
  }
}

// 5. degree (sum over shards) -> dinv
__global__ __launch_bounds__(256) void k_deg(const int* __restrict__ off2,
                                             float* __restrict__ dinv,
                                             int n, int nslice) {
  int i = blockIdx.x * 256 + threadIdx.x;
  if (i >= n) return;
  int deg = 0;
  for (int s = 0; s < nslice; ++s)
    deg += off2[(size_t)s * n + i + 1] - off2[(size_t)s * n + i];
  dinv[i] = rsqrtf((float)(deg + 1));  // +1 self loop
}

// ---------------------------------------------------------------------------
// 6. W -> split fp16, transposed [N][K]
// ---------------------------------------------------------------------------
__global__ __launch_bounds__(256) void k_castWT(const float* __restrict__ W,
                                                _Float16* __restrict__ WhT,
                                                _Float16* __restrict__ WlT,
                                                int K, int N) {
  int i = blockIdx.x * 256 + threadIdx.x;
  if (i >= K * N) return;
  int n = i % N, k = i / N;
  float v = W[i];
  _Float16 h = (_Float16)v;
  WhT[(size_t)n * K + k] = h;
  WlT[(size_t)n * K + k] = (_Float16)(v - (float)h);
}

// ---------------------------------------------------------------------------
// 7. k_gemm1: h1[M,256] = fp16(x[M,256] @ W1), split-fp16 3-term, 128x256 tile.
// ---------------------------------------------------------------------------
__global__ __launch_bounds__(256, 2) void k_gemm1(
    const float* __restrict__ A, const _Float16* __restrict__ BhT,
    const _Float16* __restrict__ BlT, _Float16* __restrict__ C,
    int M, int N, int K) {
  __shared__ _Float16 Ah[128][40];
  __shared__ _Float16 Al[128][40];

  const int tid = threadIdx.x;
  const int bm = blockIdx.x * 128;

  const int arow = tid >> 1;
  const int acol = (tid & 1) * 16;
  const bool avalid = (bm + arow) < M;
  const float* aptr = A + (size_t)(bm + arow) * K + acol;

  const int wave = tid >> 6, lane = tid & 63;
  const int wm = (wave & 1) * 64, wn = (wave >> 1) * 128;
  const int lr = lane & 15, quad = lane >> 4;

  const _Float16* bh0 = BhT + (size_t)(wn + lr) * K + quad * 8;
  const _Float16* bl0 = BlT + (size_t)(wn + lr) * K + quad * 8;

  f32x4 acc[4][8] = {};

  for (int k0 = 0; k0 < K; k0 += 32) {
    __syncthreads();
    if (avalid) {
#pragma unroll
      for (int ii = 0; ii < 4; ++ii) {
        f32x4 v = *(const f32x4*)(aptr + k0 + ii * 4);
        half4v hv, lv;
#pragma unroll
        for (int j = 0; j < 4; ++j) {
          hv[j] = (_Float16)v[j];
          lv[j] = (_Float16)(v[j] - (float)hv[j]);
        }
        *(half4v*)&Ah[arow][acol + ii * 4] = hv;
        *(half4v*)&Al[arow][acol + ii * 4] = lv;
      }
    } else {
      half4v z = {};
#pragma unroll
      for (int ii = 0; ii < 4; ++ii) {
        *(half4v*)&Ah[arow][acol + ii * 4] = z;
        *(half4v*)&Al[arow][acol + ii * 4] = z;
      }
    }
    __syncthreads();

    half8v af[4], alf[4];
#pragma unroll
    for (int mi = 0; mi < 4; ++mi) {
      af[mi] = *(const half8v*)&Ah[wm + mi * 16 + lr][quad * 8];
      alf[mi] = *(const half8v*)&Al[wm + mi * 16 + lr][quad * 8];
    }
#pragma unroll
    for (int ni = 0; ni < 8; ++ni) {
      half8v bh = *(const half8v*)(bh0 + (size_t)(ni * 16) * K + k0);
      half8v bl = *(const half8v*)(bl0 + (size_t)(ni * 16) * K + k0);
#pragma unroll
      for (int mi = 0; mi < 4; ++mi) {
        acc[mi][ni] = __builtin_amdgcn_mfma_f32_16x16x32_f16(
            af[mi], bh, acc[mi][ni], 0, 0, 0);
        acc[mi][ni] = __builtin_amdgcn_mfma_f32_16x16x32_f16(
            af[mi], bl, acc[mi][ni], 0, 0, 0);
        acc[mi][ni] = __builtin_amdgcn_mfma_f32_16x16x32_f16(
            alf[mi], bh, acc[mi][ni], 0, 0, 0);
      }
    }
  }

#pragma unroll
  for (int mi = 0; mi < 4; ++mi)
#pragma unroll
    for (int r = 0; r < 4; ++r) {
      int row = bm + wm + mi * 16 + quad * 4 + r;
      if (row < M) {
#pragma unroll
        for (int ni = 0; ni < 8; ++ni)
          C[(size_t)row * N + wn + ni * 16 + lr] = (_Float16)acc[mi][ni][r];
      }
    }
}

// ---------------------------------------------------------------------------
// 9. generic MFMA GEMM (gemm2): 128x128 tile, 2-term split-B.
// ---------------------------------------------------------------------------
template <typename AT, int NTERMS>
__global__ __launch_bounds__(256, 2) void k_gemm_mfma(
    const AT* __restrict__ A, const _Float16* __restrict__ BhT,
    const _Float16* __restrict__ BlT, _Float16* __restrict__ C,
    int M, int N, int K) {
  constexpr bool SPLITA = (NTERMS == 3);
  __shared__ _Float16 Ah[128][40];
  __shared__ _Float16 Al[SPLITA ? 128 : 1][40];

  const int tid = threadIdx.x;
  const int bm = blockIdx.x * 128;
  const int bn = blockIdx.y * 128;

  const int arow = tid >> 1;
  const int acol = (tid & 1) * 16;
  const bool avalid = (bm + arow) < M;
  const AT* aptr = A + (size_t)(bm + arow) * K + acol;

  const int wave = tid >> 6, lane = tid & 63;
  const int wm = (wave & 1) * 64, wn = (wave >> 1) * 64;
  const int lr = lane & 15, quad = lane >> 4;

  const _Float16* bh0 = BhT + (size_t)(bn + wn + lr) * K + quad * 8;
  const _Float16* bl0 = BlT + (size_t)(bn + wn + lr) * K + quad * 8;

  f32x4 acc[4][4] = {};

  for (int k0 = 0; k0 < K; k0 += 32) {
    __syncthreads();
    if (avalid) {
#pragma unroll
      for (int ii = 0; ii < 4; ++ii) {
        if constexpr (SPLITA) {
          f32x4 v = *(const f32x4*)(aptr + k0 + ii * 4);
          half4v hv, lv;
#pragma unroll
          for (int j = 0; j < 4; ++j) {
            hv[j] = (_Float16)v[j];
            lv[j] = (_Float16)(v[j] - (float)hv[j]);
          }
          *(half4v*)&Ah[arow][acol + ii * 4] = hv;
          *(half4v*)&Al[arow][acol + ii * 4] = lv;
        } else {
          half4v v = *(const half4v*)(aptr + k0 + ii * 4);
          *(half4v*)&Ah[arow][acol + ii * 4] = v;
        }
      }
    } else {
      half4v z = {};
#pragma unroll
      for (int ii = 0; ii < 4; ++ii) {
        *(half4v*)&Ah[arow][acol + ii * 4] = z;
        if constexpr (SPLITA) *(half4v*)&Al[arow][acol + ii * 4] = z;
      }
    }
    __syncthreads();

    half8v af[4], alf[4], bhf[4], blf[4];
#pragma unroll
    for (int mi = 0; mi < 4; ++mi) {
      af[mi] = *(const half8v*)&Ah[wm + mi * 16 + lr][quad * 8];
      if constexpr (SPLITA)
        alf[mi] = *(const half8v*)&Al[wm + mi * 16 + lr][quad * 8];
    }
#pragma unroll
    for (int ni = 0; ni < 4; ++ni) {
      bhf[ni] = *(const half8v*)(bh0 + (size_t)(ni * 16) * K + k0);
      blf[ni] = *(const half8v*)(bl0 + (size_t)(ni * 16) * K + k0);
    }
#pragma unroll
    for (int mi = 0; mi < 4; ++mi)
#pragma unroll
      for (int ni = 0; ni < 4; ++ni) {
        acc[mi][ni] = __builtin_amdgcn_mfma_f32_16x16x32_f16(
            af[mi], bhf[ni], acc[mi][ni], 0, 0, 0);
        acc[mi][ni] = __builtin_amdgcn_mfma_f32_16x16x32_f16(
            af[mi], blf[ni], acc[mi][ni], 0, 0, 0);
        if constexpr (SPLITA)
          acc[mi][ni] = __builtin_amdgcn_mfma_f32_16x16x32_f16(
              alf[mi], bhf[ni], acc[mi][ni], 0, 0, 0);
      }
  }

#pragma unroll
  for (int mi = 0; mi < 4; ++mi)
#pragma unroll
    for (int r = 0; r < 4; ++r) {
      int row = bm + wm + mi * 16 + quad * 4 + r;
      if (row < M) {
#pragma unroll
        for (int ni = 0; ni < 4; ++ni)
          C[(size_t)row * N + bn + wn + ni * 16 + lr] =
              (_Float16)acc[mi][ni][r];
      }
    }
}

// ---------------------------------------------------------------------------
// 8/10. Slice-resident aggregation.  One wave owns NPW=33 consecutive nodes
// with f32x2 accumulators in VGPRs for the WHOLE kernel; the src-slice loop
// is outermost, so all co-resident waves (758 blocks, 3 waves/SIMD) gather
// from the same ~1MB/XCD slice -> L2-resident.  128 channels per dispatch
// (lane covers 2 ch).  Per slice: per-slice CSR ranges off2[s*n+i..i+1];
// two 8-wide batched gather passes (MLP) + serial remainder.
// out = di*(di*h[i] + sum dinv[src]*h[src]) + bias [; relu]
// ---------------------------------------------------------------------------
template <int CS, bool RELU, typename OutT>
__global__ __launch_bounds__(256, 3) void k_agg_sl(
    const _Float16* __restrict__ h, const int* __restrict__ esrc,
    const int* __restrict__ off2, const float* __restrict__ dinv,
    const float* __restrict__ bias, OutT* __restrict__ out,
    int n, int nslice, int chbase) {
  constexpr int NPW = 33;
  const int gwave = blockIdx.x * 4 + (threadIdx.x >> 6);
  const int lane = threadIdx.x & 63;
  const int i0 = gwave * NPW;
  const int ch = chbase + lane * 2;
  const _Float16* hb = h + ch;

  f32x2 acc[NPW];
#pragma unroll
  for (int nd = 0; nd < NPW; ++nd) {
    int i = i0 + nd;
    acc[nd] = (f32x2){0.f, 0.f};
    if (i < n)
      acc[nd] = dinv[i] * __builtin_convertvector(
                              *(const half2v*)(hb + (size_t)i * CS), f32x2);
  }

  for (int s = 0; s < nslice; ++s) {
    const int* o = off2 + (size_t)s * n;
#pragma unroll
    for (int c = 0; c < NPW; c += 8) {
      int e0[8], e1[8], sv[8];
      float w[8];
      half2v hv[8];
#pragma unroll
      for (int j = 0; j < 8; ++j) {
        e0[j] = 0;
        e1[j] = 0;
        if (c + j < NPW) {
          int i = i0 + c + j;
          if (i < n) {
            e0[j] = o[i];
            e1[j] = o[i + 1];
          }
        }
      }
      // batched pass 1 (first edge of each node in this slice)
#pragma unroll
      for (int j = 0; j < 8; ++j) sv[j] = (e0[j] < e1[j]) ? esrc[e0[j]] : -1;
#pragma unroll
      for (int j = 0; j < 8; ++j)
        if (sv[j] >= 0) {
          w[j] = dinv[sv[j]];
          hv[j] = *(const half2v*)(hb + (size_t)sv[j] * CS);
        }
#pragma unroll
      for (int j = 0; j < 8; ++j)
        if (c + j < NPW && sv[j] >= 0)
          acc[c + j] += w[j] * __builtin_convertvector(hv[j], f32x2);
      // batched pass 2 (second edge)
#pragma unroll
      for (int j = 0; j < 8; ++j)
        sv[j] = (e0[j] + 1 < e1[j]) ? esrc[e0[j] + 1] : -1;
#pragma unroll
      for (int j = 0; j < 8; ++j)
        if (sv[j] >= 0) {
          w[j] = dinv[sv[j]];
          hv[j] = *(const half2v*)(hb + (size_t)sv[j] * CS);
        }
#pragma unroll
      for (int j = 0; j < 8; ++j)
        if (c + j < NPW && sv[j] >= 0)
          acc[c + j] += w[j] * __builtin_convertvector(hv[j], f32x2);
      // serial remainder (3rd+ edges; ~13% of (node,slice) pairs)
#pragma unroll
      for (int j = 0; j < 8; ++j)
        if (c + j < NPW)
          for (int e = e0[j] + 2; e < e1[j]; ++e) {
            int v2 = esrc[e];
            acc[c + j] +=
                dinv[v2] * __builtin_convertvector(
                               *(const half2v*)(hb + (size_t)v2 * CS), f32x2);
          }
    }
  }

#pragma unroll
  for (int nd = 0; nd < NPW; ++nd) {
    int i = i0 + nd;
    if (i < n) {
      f32x2 bv = *(const f32x2*)(bias + ch);
      f32x2 r = acc[nd] * dinv[i] + bv;
      if (RELU) {
        r[0] = fmaxf(r[0], 0.f);
        r[1] = fmaxf(r[1], 0.f);
      }
      if constexpr (sizeof(OutT) == 2) {
        *(half2v*)(out + (size_t)i * CS + ch) =
            __builtin_convertvector(r, half2v);
      } else {
        *(f32x2*)(out + (size_t)i * CS + ch) = r;
      }
    }
  }
}

// ---------------------------------------------------------------------------
extern "C" void kernel_launch(void* const* d_in, const int* in_sizes, int n_in,
                              void* d_out, int out_size, void* d_ws, size_t ws_size,
                              hipStream_t stream) {
  const float* x  = (const float*)d_in[0];
  const int*   ei = (const int*)d_in[1];
  const float* W1 = (const float*)d_in[2];
  const float* b1 = (const float*)d_in[3];
  const float* W2 = (const float*)d_in[4];
  const float* b2 = (const float*)d_in[5];
  float* out = (float*)d_out;

  const int IN_CH = 256, HID = 256, OUT = 128;
  const int N = in_sizes[0] / IN_CH;   // 100000
  const int E = in_sizes[1] / 2;       // 3200000
  const int* src = ei;
  const int* dst = ei + E;
  const int NB = (N + NPB - 1) / NPB;             // 391 dst buckets
  const int NSLICE = (N + (1 << SLICE_SHIFT) - 1) >> SLICE_SHIFT;  // 25
  const int nb2 = NSLICE * NB;                    // 9775

  // workspace layout
  char* p = (char*)d_ws;
  auto alloc = [&](size_t bytes) {
    void* r = (void*)p;
    p += (bytes + 255) & ~(size_t)255;
    return r;
  };
  _Float16* h1   = (_Float16*)alloc((size_t)N * HID * 2);  // reused as h2
  _Float16* h1r  = (_Float16*)alloc((size_t)N * HID * 2);
  int*      esrc = (int*)alloc((size_t)E * 4);
  uint2*    tmp  = (uint2*)alloc((size_t)E * 8);
  int*      off2 = (int*)alloc(((size_t)NSLICE * N + 1) * 4);
  float*    dinv = (float*)alloc((size_t)N * 4);
  int*      bcnt = (int*)alloc((size_t)(nb2 + 1) * 4);
  int*      bbase= (int*)alloc((size_t)(nb2 + 1) * 4);
  int*      gcur = (int*)alloc((size_t)(nb2 + 1) * 4);
  _Float16* w1h  = (_Float16*)alloc((size_t)IN_CH * HID * 2);
  _Float16* w1l  = (_Float16*)alloc((size_t)IN_CH * HID * 2);
  _Float16* w2h  = (_Float16*)alloc((size_t)HID * OUT * 2);
  _Float16* w2l  = (_Float16*)alloc((size_t)HID * OUT * 2);
  if ((size_t)(p - (char*)d_ws) > ws_size) {
    fprintf(stderr, "kernel_launch: ws too small (need %zu, have %zu)\n",
            (size_t)(p - (char*)d_ws), ws_size);
    return;
  }

  const int nBlkP = (E + PCHUNK - 1) / PCHUNK;  // 391

  // 1-2. key histogram + scan
  hipMemsetAsync(bcnt, 0, (size_t)(nb2 + 1) * 4, stream);
  k_bhist<<<nBlkP, 256, 0, stream>>>(src, dst, bcnt, E, NB, nb2);
  k_bscan2<<<1, 512, 0, stream>>>(bcnt, bbase, gcur, nb2);
  // 3. partition into (slice, dstbucket) runs
  k_partition<<<nBlkP, 256, 0, stream>>>(src, dst, gcur, tmp, E, NB, nb2);
  // 4. per-bucket sort -> esrc, off2
  k_bucket<<<dim3(NB, NSLICE), 256, 0, stream>>>(tmp, bbase, off2, esrc, N);
  // 5. dinv from shard degree sums
  k_deg<<<(N + 255) / 256, 256, 0, stream>>>(off2, dinv, N, NSLICE);
  // 6. W splits (transposed)
  k_castWT<<<(IN_CH * HID + 255) / 256, 256, 0, stream>>>(W1, w1h, w1l, IN_CH, HID);
  k_castWT<<<(HID * OUT + 255) / 256, 256, 0, stream>>>(W2, w2h, w2l, HID, OUT);
  // 7. h1 = fp16(x @ W1)
  k_gemm1<<<(N + 127) / 128, 256, 0, stream>>>(x, w1h, w1l, h1, N, HID, IN_CH);
  // 8. agg layer 1 (+bias, relu) -> h1r fp16, two 128-ch dispatches
  const int aggBlk = (N + 4 * 33 - 1) / (4 * 33);  // 758 blocks (co-resident)
  k_agg_sl<256, true, _Float16><<<aggBlk, 256, 0, stream>>>(
      h1, esrc, off2, dinv, b1, h1r, N, NSLICE, 0);
  k_agg_sl<256, true, _Float16><<<aggBlk, 256, 0, stream>>>(
      h1, esrc, off2, dinv, b1, h1r, N, NSLICE, 128);
  // 9. h2 = fp16(h1r @ W2)
  dim3 g2((N + 127) / 128, OUT / 128);
  k_gemm_mfma<_Float16, 2><<<g2, 256, 0, stream>>>(h1r, w2h, w2l, h1, N, OUT, HID);
  // 10. agg layer 2 (+bias) -> out fp32
  k_agg_sl<128, false, float><<<aggBlk, 256, 0, stream>>>(
      h1, esrc, off2, dinv, b2, out, N, NSLICE, 0);
}

// Round 6
// 1288.764 us; speedup vs baseline: 1.2361x; 1.2361x over previous
//
#include <hip/hip_runtime.h>
#include <cstdio>

// ---------------------------------------------------------------------------
// GCN 2-layer forward on MI355X.  Round 10: slice-resident agg, lean stream.
// Pipeline:
//   1. k_bhist:     histogram of key=(src>>12)*NB+(dst>>8)   (25x391 buckets)
//   2. k_bscan2:    scan 9775 buckets -> bbase[], init gcur[]
//   3. k_partition: edges -> tmp[] packed (src,dst), (slice,dstbucket)-order
//   4. k_bucket:    per-bucket LDS counting sort -> esrc[], off2[s*N+i]
//   5. k_deg:       degree from off2 shards -> dinv[]
//   6. k_evec:      evec[e] = (src, bits(dinv[src]))  -- packed edge stream
//   7. k_castWT:    W -> (Wh,Wl) fp16 split, TRANSPOSED [N][K]
//   8. k_gemm1:     h1 = fp16(x @ W1), 128x256 tile
//   9. k_agg2 x2:   layer-1 agg, 128ch/dispatch, src-slice sweep
//  10. k_gemm_mfma: h2 = fp16(h1r @ W2)
//  11. k_agg2:      layer-2 agg + bias -> out fp32
// R5 proved the slice sweep cuts agg FETCH 800->287MB (compulsory); R5's
// kernel was latency/overhead-bound (occ 32%, 2-level dep chains, masked
// batches).  R10: packed evec (1 load = addr+weight), NPW=32 (n%32==0 ->
// maskless), 4 blk/CU co-resident (782<=1024), 12 independent gather slots
// in flight via wave-uniform guarded 3-pass batching, SGPR cursors.
// ---------------------------------------------------------------------------

#define NPB 256        // nodes per dst bucket (bucket = dst >> 8)
#define PCHUNK 8192    // edges per partition block
#define SLICE_SHIFT 12 // src slice = src >> 12  (4096 rows)
#define MAXB 12544     // LDS histogram capacity (>= NSLICE*NB = 9775)

typedef _Float16 half2v __attribute__((ext_vector_type(2)));
typedef _Float16 half4v __attribute__((ext_vector_type(4)));
typedef _Float16 half8v __attribute__((ext_vector_type(8)));
typedef float    f32x2  __attribute__((ext_vector_type(2)));
typedef float    f32x4  __attribute__((ext_vector_type(4)));

// 1. bucket histogram over (slice, dstbucket) keys, LDS-privatized
__global__ __launch_bounds__(256) void k_bhist(const int* __restrict__ src,
                                               const int* __restrict__ dst,
                                               int* __restrict__ bcnt,
                                               int e, int nb, int nb2) {
  __shared__ int h[MAXB];
  for (int i = threadIdx.x; i < nb2; i += 256) h[i] = 0;
  __syncthreads();
  int c0 = blockIdx.x * PCHUNK;
  int c1 = min(c0 + PCHUNK, e);
  for (int i = c0 + threadIdx.x; i < c1; i += 256) {
    int key = ((unsigned)src[i] >> SLICE_SHIFT) * nb + ((unsigned)dst[i] >> 8);
    atomicAdd(&h[key], 1);
  }
  __syncthreads();
  for (int i = threadIdx.x; i < nb2; i += 256)
    if (h[i]) atomicAdd(&bcnt[i], h[i]);
}

// 2. single-block scan of nb2 bucket counts -> bbase[0..nb2], gcur init
__global__ __launch_bounds__(512) void k_bscan2(const int* __restrict__ bcnt,
                                                int* __restrict__ bbase,
                                                int* __restrict__ gcur,
                                                int nb2) {
  __shared__ int sm[512];
  const int tid = threadIdx.x;
  const int chunk = (nb2 + 511) >> 9;
  const int c0 = min(tid * chunk, nb2);
  const int c1 = min(c0 + chunk, nb2);
  int sum = 0;
  for (int j = c0; j < c1; ++j) sum += bcnt[j];
  sm[tid] = sum;
  __syncthreads();
  for (int d = 1; d < 512; d <<= 1) {
    int t = (tid >= d) ? sm[tid - d] : 0;
    __syncthreads();
    sm[tid] += t;
    __syncthreads();
  }
  int run = (tid == 0) ? 0 : sm[tid - 1];
  for (int j = c0; j < c1; ++j) {
    bbase[j] = run;
    gcur[j] = run;
    run += bcnt[j];
  }
  if (tid == 511) bbase[nb2] = run;
}

// 3. partition: edges -> tmp[] in (slice, dstbucket)-contiguous runs.
__global__ __launch_bounds__(256) void k_partition(const int* __restrict__ src,
                                                   const int* __restrict__ dst,
                                                   int* __restrict__ gcur,
                                                   uint2* __restrict__ tmp,
                                                   int e, int nb, int nb2) {
  __shared__ int hist[MAXB];
  for (int i = threadIdx.x; i < nb2; i += 256) hist[i] = 0;
  __syncthreads();
  int c0 = blockIdx.x * PCHUNK;
  int c1 = min(c0 + PCHUNK, e);
  for (int i = c0 + threadIdx.x; i < c1; i += 256) {
    int key = ((unsigned)src[i] >> SLICE_SHIFT) * nb + ((unsigned)dst[i] >> 8);
    atomicAdd(&hist[key], 1);
  }
  __syncthreads();
  for (int i = threadIdx.x; i < nb2; i += 256) {
    int c = hist[i];
    hist[i] = c ? atomicAdd(&gcur[i], c) : 0;  // count -> global cursor
  }
  __syncthreads();
  for (int i = c0 + threadIdx.x; i < c1; i += 256) {
    int s = src[i], d = dst[i];
    int key = ((unsigned)s >> SLICE_SHIFT) * nb + ((unsigned)d >> 8);
    int pos = atomicAdd(&hist[key], 1);
    uint2 v;
    v.x = (unsigned)s;
    v.y = (unsigned)d;
    tmp[pos] = v;
  }
}

// 4. per-(slice,dstbucket) counting sort by dstLocal -> esrc[], off2[s*N+i].
__global__ __launch_bounds__(256) void k_bucket(const uint2* __restrict__ tmp,
                                                const int* __restrict__ bbase,
                                                int* __restrict__ off2,
                                                int* __restrict__ esrc, int n) {
  __shared__ int lcnt[NPB];
  __shared__ int lsum[NPB];
  __shared__ int lcur[NPB];
  const int b = blockIdx.y * gridDim.x + blockIdx.x;
  const int tid = threadIdx.x;
  const int r0 = blockIdx.x << 8;
  const int nn = min(NPB, n - r0);
  const int lo = bbase[b], hi = bbase[b + 1];

  lcnt[tid] = 0;
  __syncthreads();
  for (int i = lo + tid; i < hi; i += 256)
    atomicAdd(&lcnt[tmp[i].y & (NPB - 1)], 1);
  __syncthreads();
  lsum[tid] = lcnt[tid];
  __syncthreads();
  for (int d = 1; d < NPB; d <<= 1) {
    int t = (tid >= d) ? lsum[tid - d] : 0;
    __syncthreads();
    lsum[tid] += t;
    __syncthreads();
  }
  int ex = (tid == 0) ? 0 : lsum[tid - 1];
  if (tid < nn) {
    off2[(size_t)blockIdx.y * n + r0 + tid] = lo + ex;
    lcur[tid] = lo + ex;
  }
  if (blockIdx.y == gridDim.y - 1 && r0 + nn == n && tid == 0)
    off2[(size_t)gridDim.y * n] = hi;
  __syncthreads();
  for (int i = lo + tid; i < hi; i += 256) {
    uint2 t2 = tmp[i];
    int pos = atomicAdd(&lcur[t2.y & (NPB - 1)], 1);
    esrc[pos] = (int)t2.x;
  }
}

// 5. degree (sum over shards) -> dinv
__global__ __launch_bounds__(256) void k_deg(const int* __restrict__ off2,
                                             float* __restrict__ dinv,
                                             int n, int nslice) {
  int i = blockIdx.x * 256 + threadIdx.x;
  if (i >= n) return;
  int deg = 0;
  for (int s = 0; s < nslice; ++s)
    deg += off2[(size_t)s * n + i + 1] - off2[(size_t)s * n + i];
  dinv[i] = rsqrtf((float)(deg + 1));  // +1 self loop
}

// 6. packed edge stream: evec[e] = (src, f32 bits of dinv[src])
__global__ __launch_bounds__(256) void k_evec(const int* __restrict__ esrc,
                                              const float* __restrict__ dinv,
                                              uint2* __restrict__ evec, int e) {
  int i = blockIdx.x * 256 + threadIdx.x;
  if (i >= e) return;
  int s = esrc[i];
  uint2 v;
  v.x = (unsigned)s;
  v.y = __float_as_uint(dinv[s]);
  evec[i] = v;
}

// ---------------------------------------------------------------------------
// 7. W -> split fp16, transposed [N][K]
// ---------------------------------------------------------------------------
__global__ __launch_bounds__(256) void k_castWT(const float* __restrict__ W,
                                                _Float16* __restrict__ WhT,
                                                _Float16* __restrict__ WlT,
                                                int K, int N) {
  int i = blockIdx.x * 256 + threadIdx.x;
  if (i >= K * N) return;
  int n = i % N, k = i / N;
  float v = W[i];
  _Float16 h = (_Float16)v;
  WhT[(size_t)n * K + k] = h;
  WlT[(size_t)n * K + k] = (_Float16)(v - (float)h);
}

// ---------------------------------------------------------------------------
// 8. k_gemm1: h1[M,256] = fp16(x[M,256] @ W1), split-fp16 3-term, 128x256 tile.
// ---------------------------------------------------------------------------
__global__ __launch_bounds__(256, 2) void k_gemm1(
    const float* __restrict__ A, const _Float16* __restrict__ BhT,
    const _Float16* __restrict__ BlT, _Float16* __restrict__ C,
    int M, int N, int K) {
  __shared__ _Float16 Ah[128][40];
  __shared__ _Float16 Al[128][40];

  const int tid = threadIdx.x;
  const int bm = blockIdx.x * 128;

  const int arow = tid >> 1;
  const int acol = (tid & 1) * 16;
  const bool avalid = (bm + arow) < M;
  const float* aptr = A + (size_t)(bm + arow) * K + acol;

  const int wave = tid >> 6, lane = tid & 63;
  const int wm = (wave & 1) * 64, wn = (wave >> 1) * 128;
  const int lr = lane & 15, quad = lane >> 4;

  const _Float16* bh0 = BhT + (size_t)(wn + lr) * K + quad * 8;
  const _Float16* bl0 = BlT + (size_t)(wn + lr) * K + quad * 8;

  f32x4 acc[4][8] = {};

  for (int k0 = 0; k0 < K; k0 += 32) {
    __syncthreads();
    if (avalid) {
#pragma unroll
      for (int ii = 0; ii < 4; ++ii) {
        f32x4 v = *(const f32x4*)(aptr + k0 + ii * 4);
        half4v hv, lv;
#pragma unroll
        for (int j = 0; j < 4; ++j) {
          hv[j] = (_Float16)v[j];
          lv[j] = (_Float16)(v[j] - (float)hv[j]);
        }
        *(half4v*)&Ah[arow][acol + ii * 4] = hv;
        *(half4v*)&Al[arow][acol + ii * 4] = lv;
      }
    } else {
      half4v z = {};
#pragma unroll
      for (int ii = 0; ii < 4; ++ii) {
        *(half4v*)&Ah[arow][acol + ii * 4] = z;
        *(half4v*)&Al[arow][acol + ii * 4] = z;
      }
    }
    __syncthreads();

    half8v af[4], alf[4];
#pragma unroll
    for (int mi = 0; mi < 4; ++mi) {
      af[mi] = *(const half8v*)&Ah[wm + mi * 16 + lr][quad * 8];
      alf[mi] = *(const half8v*)&Al[wm + mi * 16 + lr][quad * 8];
    }
#pragma unroll
    for (int ni = 0; ni < 8; ++ni) {
      half8v bh = *(const half8v*)(bh0 + (size_t)(ni * 16) * K + k0);
      half8v bl = *(const half8v*)(bl0 + (size_t)(ni * 16) * K + k0);
#pragma unroll
      for (int mi = 0; mi < 4; ++mi) {
        acc[mi][ni] = __builtin_amdgcn_mfma_f32_16x16x32_f16(
            af[mi], bh, acc[mi][ni], 0, 0, 0);
        acc[mi][ni] = __builtin_amdgcn_mfma_f32_16x16x32_f16(
            af[mi], bl, acc[mi][ni], 0, 0, 0);
        acc[mi][ni] = __builtin_amdgcn_mfma_f32_16x16x32_f16(
            alf[mi], bh, acc[mi][ni], 0, 0, 0);
      }
    }
  }

#pragma unroll
  for (int mi = 0; mi < 4; ++mi)
#pragma unroll
    for (int r = 0; r < 4; ++r) {
      int row = bm + wm + mi * 16 + quad * 4 + r;
      if (row < M) {
#pragma unroll
        for (int ni = 0; ni < 8; ++ni)
          C[(size_t)row * N + wn + ni * 16 + lr] = (_Float16)acc[mi][ni][r];
      }
    }
}

// ---------------------------------------------------------------------------
// 10. generic MFMA GEMM (gemm2): 128x128 tile, 2-term split-B.
// ---------------------------------------------------------------------------
template <typename AT, int NTERMS>
__global__ __launch_bounds__(256, 2) void k_gemm_mfma(
    const AT* __restrict__ A, const _Float16* __restrict__ BhT,
    const _Float16* __restrict__ BlT, _Float16* __restrict__ C,
    int M, int N, int K) {
  constexpr bool SPLITA = (NTERMS == 3);
  __shared__ _Float16 Ah[128][40];
  __shared__ _Float16 Al[SPLITA ? 128 : 1][40];

  const int tid = threadIdx.x;
  const int bm = blockIdx.x * 128;
  const int bn = blockIdx.y * 128;

  const int arow = tid >> 1;
  const int acol = (tid & 1) * 16;
  const bool avalid = (bm + arow) < M;
  const AT* aptr = A + (size_t)(bm + arow) * K + acol;

  const int wave = tid >> 6, lane = tid & 63;
  const int wm = (wave & 1) * 64, wn = (wave >> 1) * 64;
  const int lr = lane & 15, quad = lane >> 4;

  const _Float16* bh0 = BhT + (size_t)(bn + wn + lr) * K + quad * 8;
  const _Float16* bl0 = BlT + (size_t)(bn + wn + lr) * K + quad * 8;

  f32x4 acc[4][4] = {};

  for (int k0 = 0; k0 < K; k0 += 32) {
    __syncthreads();
    if (avalid) {
#pragma unroll
      for (int ii = 0; ii < 4; ++ii) {
        if constexpr (SPLITA) {
          f32x4 v = *(const f32x4*)(aptr + k0 + ii * 4);
          half4v hv, lv;
#pragma unroll
          for (int j = 0; j < 4; ++j) {
            hv[j] = (_Float16)v[j];
            lv[j] = (_Float16)(v[j] - (float)hv[j]);
          }
          *(half4v*)&Ah[arow][acol + ii * 4] = hv;
          *(half4v*)&Al[arow][acol + ii * 4] = lv;
        } else {
          half4v v = *(const half4v*)(aptr + k0 + ii * 4);
          *(half4v*)&Ah[arow][acol + ii * 4] = v;
        }
      }
    } else {
      half4v z = {};
#pragma unroll
      for (int ii = 0; ii < 4; ++ii) {
        *(half4v*)&Ah[arow][acol + ii * 4] = z;
        if constexpr (SPLITA) *(half4v*)&Al[arow][acol + ii * 4] = z;
      }
    }
    __syncthreads();

    half8v af[4], alf[4], bhf[4], blf[4];
#pragma unroll
    for (int mi = 0; mi < 4; ++mi) {
      af[mi] = *(const half8v*)&Ah[wm + mi * 16 + lr][quad * 8];
      if constexpr (SPLITA)
        alf[mi] = *(const half8v*)&Al[wm + mi * 16 + lr][quad * 8];
    }
#pragma unroll
    for (int ni = 0; ni < 4; ++ni) {
      bhf[ni] = *(const half8v*)(bh0 + (size_t)(ni * 16) * K + k0);
      blf[ni] = *(const half8v*)(bl0 + (size_t)(ni * 16) * K + k0);
    }
#pragma unroll
    for (int mi = 0; mi < 4; ++mi)
#pragma unroll
      for (int ni = 0; ni < 4; ++ni) {
        acc[mi][ni] = __builtin_amdgcn_mfma_f32_16x16x32_f16(
            af[mi], bhf[ni], acc[mi][ni], 0, 0, 0);
        acc[mi][ni] = __builtin_amdgcn_mfma_f32_16x16x32_f16(
            af[mi], blf[ni], acc[mi][ni], 0, 0, 0);
        if constexpr (SPLITA)
          acc[mi][ni] = __builtin_amdgcn_mfma_f32_16x16x32_f16(
              alf[mi], bhf[ni], acc[mi][ni], 0, 0, 0);
      }
  }

#pragma unroll
  for (int mi = 0; mi < 4; ++mi)
#pragma unroll
    for (int r = 0; r < 4; ++r) {
      int row = bm + wm + mi * 16 + quad * 4 + r;
      if (row < M) {
#pragma unroll
        for (int ni = 0; ni < 4; ++ni)
          C[(size_t)row * N + bn + wn + ni * 16 + lr] =
              (_Float16)acc[mi][ni][r];
      }
    }
}

// ---------------------------------------------------------------------------
// 9/11. Slice-resident aggregation, lean stream.
// Wave owns NPW=32 consecutive nodes (n%32==0 -> waves are full or empty,
// no per-node masks).  Lane covers 2 channels (f32x2 acc = 64 VGPR).
// 782 blocks, 4 blk/CU co-resident (<=1024 slots) -> machine-wide slice
// lockstep.  Per slice, per 4-node batch: SGPR cursors from off2; passes
// 0..2 give 12 independent evec->gather chains in flight (wave-uniform
// guards, execz-skipped); serial remainder only for k>=4 (~5%).
// evec = (src, bits(dinv[src])): 1 load = address + weight.
// ---------------------------------------------------------------------------
template <int CS, bool RELU, typename OutT>
__global__ __launch_bounds__(256, 4) void k_agg2(
    const _Float16* __restrict__ h, const uint2* __restrict__ evec,
    const int* __restrict__ off2, const float* __restrict__ dinv,
    const float* __restrict__ bias, OutT* __restrict__ out,
    int n, int nslice, int chbase) {
  constexpr int NPW = 32;
  const int wave = threadIdx.x >> 6, lane = threadIdx.x & 63;
  const int i0 = (blockIdx.x * 4 + wave) * NPW;
  if (i0 >= n) return;  // fully-empty trailing waves only (n % 32 == 0)
  const int ch = chbase + lane * 2;
  const _Float16* hb = h + ch;

  f32x2 acc[NPW];
  // self term, batched 8-wide
#pragma unroll
  for (int c = 0; c < NPW; c += 8) {
    float w[8];
    half2v hv[8];
#pragma unroll
    for (int j = 0; j < 8; ++j) w[j] = dinv[i0 + c + j];
#pragma unroll
    for (int j = 0; j < 8; ++j)
      hv[j] = *(const half2v*)(hb + (size_t)(i0 + c + j) * CS);
#pragma unroll
    for (int j = 0; j < 8; ++j)
      acc[c + j] = w[j] * __builtin_convertvector(hv[j], f32x2);
  }

  for (int s = 0; s < nslice; ++s) {
    const int* o = off2 + (size_t)s * n + i0;
#pragma unroll
    for (int c = 0; c < NPW; c += 4) {
      int eb[5];
#pragma unroll
      for (int j = 0; j < 5; ++j)
        eb[j] = __builtin_amdgcn_readfirstlane(o[c + j]);

      float w[12];
      half2v hv[12];
      // issue phase: up to 12 independent evec->gather chains
#pragma unroll
      for (int p = 0; p < 3; ++p)
#pragma unroll
        for (int j = 0; j < 4; ++j) {
          int idx = eb[j] + p;
          if (idx < eb[j + 1]) {
            uint2 ev = evec[idx];
            w[p * 4 + j] = __uint_as_float(ev.y);
            hv[p * 4 + j] = *(const half2v*)(hb + (size_t)ev.x * CS);
          }
        }
      // accumulate phase
#pragma unroll
      for (int p = 0; p < 3; ++p)
#pragma unroll
        for (int j = 0; j < 4; ++j) {
          if (eb[j] + p < eb[j + 1])
            acc[c + j] +=
                w[p * 4 + j] * __builtin_convertvector(hv[p * 4 + j], f32x2);
        }
      // serial remainder: 4th+ edge of a (node,slice) pair (~5%)
#pragma unroll
      for (int j = 0; j < 4; ++j)
        for (int e = eb[j] + 3; e < eb[j + 1]; ++e) {
          uint2 ev = evec[e];
          acc[c + j] += __uint_as_float(ev.y) *
                        __builtin_convertvector(
                            *(const half2v*)(hb + (size_t)ev.x * CS), f32x2);
        }
    }
  }

  const f32x2 bv = *(const f32x2*)(bias + ch);
#pragma unroll
  for (int nd = 0; nd < NPW; ++nd) {
    int i = i0 + nd;
    f32x2 r = acc[nd] * dinv[i] + bv;
    if (RELU) {
      r[0] = fmaxf(r[0], 0.f);
      r[1] = fmaxf(r[1], 0.f);
    }
    if constexpr (sizeof(OutT) == 2) {
      *(half2v*)(out + (size_t)i * CS + ch) = __builtin_convertvector(r, half2v);
    } else {
      *(f32x2*)(out + (size_t)i * CS + ch) = r;
    }
  }
}

// ---------------------------------------------------------------------------
extern "C" void kernel_launch(void* const* d_in, const int* in_sizes, int n_in,
                              void* d_out, int out_size, void* d_ws, size_t ws_size,
                              hipStream_t stream) {
  const float* x  = (const float*)d_in[0];
  const int*   ei = (const int*)d_in[1];
  const float* W1 = (const float*)d_in[2];
  const float* b1 = (const float*)d_in[3];
  const float* W2 = (const float*)d_in[4];
  const float* b2 = (const float*)d_in[5];
  float* out = (float*)d_out;

  const int IN_CH = 256, HID = 256, OUT = 128;
  const int N = in_sizes[0] / IN_CH;   // 100000
  const int E = in_sizes[1] / 2;       // 3200000
  const int* src = ei;
  const int* dst = ei + E;
  const int NB = (N + NPB - 1) / NPB;             // 391 dst buckets
  const int NSLICE = (N + (1 << SLICE_SHIFT) - 1) >> SLICE_SHIFT;  // 25
  const int nb2 = NSLICE * NB;                    // 9775

  // workspace layout
  char* p = (char*)d_ws;
  auto alloc = [&](size_t bytes) {
    void* r = (void*)p;
    p += (bytes + 255) & ~(size_t)255;
    return r;
  };
  _Float16* h1   = (_Float16*)alloc((size_t)N * HID * 2);  // reused as h2
  _Float16* h1r  = (_Float16*)alloc((size_t)N * HID * 2);
  int*      esrc = (int*)alloc((size_t)E * 4);
  uint2*    tmp  = (uint2*)alloc((size_t)E * 8);   // reused as evec
  int*      off2 = (int*)alloc(((size_t)NSLICE * N + 1) * 4);
  float*    dinv = (float*)alloc((size_t)N * 4);
  int*      bcnt = (int*)alloc((size_t)(nb2 + 1) * 4);
  int*      bbase= (int*)alloc((size_t)(nb2 + 1) * 4);
  int*      gcur = (int*)alloc((size_t)(nb2 + 1) * 4);
  _Float16* w1h  = (_Float16*)alloc((size_t)IN_CH * HID * 2);
  _Float16* w1l  = (_Float16*)alloc((size_t)IN_CH * HID * 2);
  _Float16* w2h  = (_Float16*)alloc((size_t)HID * OUT * 2);
  _Float16* w2l  = (_Float16*)alloc((size_t)HID * OUT * 2);
  if ((size_t)(p - (char*)d_ws) > ws_size) {
    fprintf(stderr, "kernel_launch: ws too small (need %zu, have %zu)\n",
            (size_t)(p - (char*)d_ws), ws_size);
    return;
  }
  uint2* evec = tmp;  // tmp is dead after k_bucket

  const int nBlkP = (E + PCHUNK - 1) / PCHUNK;  // 391

  // 1-2. key histogram + scan
  hipMemsetAsync(bcnt, 0, (size_t)(nb2 + 1) * 4, stream);
  k_bhist<<<nBlkP, 256, 0, stream>>>(src, dst, bcnt, E, NB, nb2);
  k_bscan2<<<1, 512, 0, stream>>>(bcnt, bbase, gcur, nb2);
  // 3. partition into (slice, dstbucket) runs
  k_partition<<<nBlkP, 256, 0, stream>>>(src, dst, gcur, tmp, E, NB, nb2);
  // 4. per-bucket sort -> esrc, off2
  k_bucket<<<dim3(NB, NSLICE), 256, 0, stream>>>(tmp, bbase, off2, esrc, N);
  // 5. dinv from shard degree sums
  k_deg<<<(N + 255) / 256, 256, 0, stream>>>(off2, dinv, N, NSLICE);
  // 6. packed edge stream (overwrites tmp)
  k_evec<<<(E + 255) / 256, 256, 0, stream>>>(esrc, dinv, evec, E);
  // 7. W splits (transposed)
  k_castWT<<<(IN_CH * HID + 255) / 256, 256, 0, stream>>>(W1, w1h, w1l, IN_CH, HID);
  k_castWT<<<(HID * OUT + 255) / 256, 256, 0, stream>>>(W2, w2h, w2l, HID, OUT);
  // 8. h1 = fp16(x @ W1)
  k_gemm1<<<(N + 127) / 128, 256, 0, stream>>>(x, w1h, w1l, h1, N, HID, IN_CH);
  // 9. agg layer 1 (+bias, relu) -> h1r fp16, two 128-ch dispatches
  const int aggBlk = (N + 4 * 32 - 1) / (4 * 32);  // 782 blocks, co-resident
  k_agg2<256, true, _Float16><<<aggBlk, 256, 0, stream>>>(
      h1, evec, off2, dinv, b1, h1r, N, NSLICE, 0);
  k_agg2<256, true, _Float16><<<aggBlk, 256, 0, stream>>>(
      h1, evec, off2, dinv, b1, h1r, N, NSLICE, 128);
  // 10. h2 = fp16(h1r @ W2)
  dim3 g2((N + 127) / 128, OUT / 128);
  k_gemm_mfma<_Float16, 2><<<g2, 256, 0, stream>>>(h1r, w2h, w2l, h1, N, OUT, HID);
  // 11. agg layer 2 (+bias) -> out fp32
  k_agg2<128, false, float><<<aggBlk, 256, 0, stream>>>(
      h1, evec, off2, dinv, b2, out, N, NSLICE, 0);
}

// Round 7
// 794.180 us; speedup vs baseline: 2.0059x; 1.6228x over previous
//
#include <hip/hip_runtime.h>
#include <cstdio>

// ---------------------------------------------------------------------------
// GCN 2-layer forward on MI355X.  Round 11: barrier-free direct-fragment GEMMs.
// Pipeline:
//   1. k_bhist:     bucket histogram of dst>>8  (LDS-privatized)
//   2. k_bscan:     scan 391 buckets -> bbase[], init gcur[]
//   3. k_partition: edges -> tmp[] packed (src,dst), bucket-partitioned
//   4. k_bucket:    per-bucket LDS sort -> esrc[], off[], dinv[]
//   5. k_castWT:    W -> (Wh,Wl) fp16 split, TRANSPOSED [N][K]
//   6. k_castX:     x -> (xh,xl) fp16 split [M][K]  (xh aliases h1r, xl tmp)
//   7. k_gemm1d:    h1 = fp16(x @ W1): NO LDS, NO barriers; A and B fragments
//                   loaded directly from global (16B/lane), 3-term split
//   8. k_agg (streaming, R4): agg1 + bias + relu -> h1r fp16
//   9. k_gemm2d:    h2 = fp16(h1r @ W2), direct fragments, 2-term
//  10. k_agg:       agg2 + bias -> out fp32
// R5/R6 verdict: slice-resident agg cuts FETCH to compulsory but serializes
// (~200 dependent rounds) and halves occupancy -> 2.6x worse per byte than
// streaming.  Streaming agg (342us, FETCH 800MB, 3.85TB/s fill path) is the
// practical floor -> reverted.  This round attacks the ~400us non-agg mass:
// gemm1's per-K-step fp32-load + split-cast + 2-barrier staging is replaced
// by a one-shot cast pass + barrier-free direct-fragment K-loop.
// ---------------------------------------------------------------------------

#define NPB 256        // nodes per bucket (power of 2: bucket = dst >> 8)
#define PCHUNK 8192    // edges per partition block

typedef _Float16 half4v __attribute__((ext_vector_type(4)));
typedef _Float16 half8v __attribute__((ext_vector_type(8)));
typedef float    f32x4  __attribute__((ext_vector_type(4)));
typedef float    f32x8  __attribute__((ext_vector_type(8)));

// 1. bucket histogram, LDS-privatized
__global__ __launch_bounds__(256) void k_bhist(const int* __restrict__ dst,
                                               int* __restrict__ bcnt,
                                               int e, int nb) {
  __shared__ int h[512];
  for (int i = threadIdx.x; i < nb; i += 256) h[i] = 0;
  __syncthreads();
  int c0 = blockIdx.x * PCHUNK;
  int c1 = min(c0 + PCHUNK, e);
  for (int i = c0 + threadIdx.x; i < c1; i += 256)
    atomicAdd(&h[dst[i] >> 8], 1);
  __syncthreads();
  for (int i = threadIdx.x; i < nb; i += 256)
    if (h[i]) atomicAdd(&bcnt[i], h[i]);
}

// 2. single-block scan of bucket counts -> bbase[0..nb], gcur init
__global__ __launch_bounds__(512) void k_bscan(const int* __restrict__ bcnt,
                                               int* __restrict__ bbase,
                                               int* __restrict__ gcur, int nb) {
  __shared__ int sm[512];
  int tid = threadIdx.x;
  sm[tid] = (tid < nb) ? bcnt[tid] : 0;
  __syncthreads();
  for (int d = 1; d < 512; d <<= 1) {
    int t = (tid >= d) ? sm[tid - d] : 0;
    __syncthreads();
    sm[tid] += t;
    __syncthreads();
  }
  int ex = (tid == 0) ? 0 : sm[tid - 1];
  if (tid < nb) {
    bbase[tid] = ex;
    gcur[tid] = ex;
  }
  if (tid == nb) bbase[nb] = sm[nb - 1];
}

// 3. bucket partition: contiguous runs of packed (src,dst) per (block,bucket)
__global__ __launch_bounds__(256) void k_partition(const int* __restrict__ src,
                                                   const int* __restrict__ dst,
                                                   int* __restrict__ gcur,
                                                   uint2* __restrict__ tmp,
                                                   int e, int nb) {
  __shared__ int hist[512];
  __shared__ int base[512];
  for (int i = threadIdx.x; i < nb; i += 256) hist[i] = 0;
  __syncthreads();
  int c0 = blockIdx.x * PCHUNK;
  int c1 = min(c0 + PCHUNK, e);
  for (int i = c0 + threadIdx.x; i < c1; i += 256)
    atomicAdd(&hist[dst[i] >> 8], 1);
  __syncthreads();
  for (int i = threadIdx.x; i < nb; i += 256) {
    int c = hist[i];
    base[i] = c ? atomicAdd(&gcur[i], c) : 0;
    hist[i] = 0;  // reuse as local cursor
  }
  __syncthreads();
  for (int i = c0 + threadIdx.x; i < c1; i += 256) {
    int d = dst[i];
    int b = d >> 8;
    int pos = base[b] + atomicAdd(&hist[b], 1);
    uint2 v;
    v.x = (unsigned)src[i];
    v.y = (unsigned)d;
    tmp[pos] = v;
  }
}

// 4. per-bucket sort: produce esrc (grouped by dst), off[], dinv[]
__global__ __launch_bounds__(256) void k_bucket(const uint2* __restrict__ tmp,
                                                const int* __restrict__ bbase,
                                                int* __restrict__ off,
                                                float* __restrict__ dinv,
                                                int* __restrict__ esrc, int n) {
  __shared__ int lcnt[NPB];
  __shared__ int lsum[NPB];
  __shared__ int lcur[NPB];
  const int b = blockIdx.x;
  const int tid = threadIdx.x;
  const int r0 = b << 8;
  const int nn = min(NPB, n - r0);
  const int lo = bbase[b], hi = bbase[b + 1];

  lcnt[tid] = 0;
  __syncthreads();
  for (int i = lo + tid; i < hi; i += 256)
    atomicAdd(&lcnt[tmp[i].y & (NPB - 1)], 1);
  __syncthreads();
  lsum[tid] = lcnt[tid];
  __syncthreads();
  for (int d = 1; d < NPB; d <<= 1) {
    int t = (tid >= d) ? lsum[tid - d] : 0;
    __syncthreads();
    lsum[tid] += t;
    __syncthreads();
  }
  int ex = (tid == 0) ? 0 : lsum[tid - 1];
  if (tid < nn) {
    off[r0 + tid] = lo + ex;
    dinv[r0 + tid] = rsqrtf((float)(lcnt[tid] + 1));  // +1 self loop
    lcur[tid] = lo + ex;
  }
  if (r0 + nn == n && tid == 0) off[n] = hi;
  __syncthreads();
  for (int i = lo + tid; i < hi; i += 256) {
    uint2 t2 = tmp[i];
    int pos = atomicAdd(&lcur[t2.y & (NPB - 1)], 1);
    esrc[pos] = (int)t2.x;
  }
}

// ---------------------------------------------------------------------------
// 5. W -> split fp16, transposed [N][K] (B-fragment = contiguous 16B)
// ---------------------------------------------------------------------------
__global__ __launch_bounds__(256) void k_castWT(const float* __restrict__ W,
                                                _Float16* __restrict__ WhT,
                                                _Float16* __restrict__ WlT,
                                                int K, int N) {
  int i = blockIdx.x * 256 + threadIdx.x;
  if (i >= K * N) return;
  int n = i % N, k = i / N;      // coalesced read of W[k][n]
  float v = W[i];
  _Float16 h = (_Float16)v;
  WhT[(size_t)n * K + k] = h;
  WlT[(size_t)n * K + k] = (_Float16)(v - (float)h);
}

// ---------------------------------------------------------------------------
// 6. x -> (xh, xl) fp16 split, row-major [M][K], vectorized 4 elems/lane.
// ---------------------------------------------------------------------------
__global__ __launch_bounds__(256) void k_castX(const float* __restrict__ X,
                                               _Float16* __restrict__ Xh,
                                               _Float16* __restrict__ Xl,
                                               int total4) {
  int i = blockIdx.x * 256 + threadIdx.x;
  if (i >= total4) return;
  f32x4 v = *(const f32x4*)(X + (size_t)i * 4);
  half4v h, l;
#pragma unroll
  for (int j = 0; j < 4; ++j) {
    h[j] = (_Float16)v[j];
    l[j] = (_Float16)(v[j] - (float)h[j]);
  }
  *(half4v*)(Xh + (size_t)i * 4) = h;
  *(half4v*)(Xl + (size_t)i * 4) = l;
}

// ---------------------------------------------------------------------------
// 7. k_gemm1d: h1[M,256] = fp16(x @ W1), 3-term split, DIRECT fragments.
// No LDS, no barriers: A-fragment (16B/lane) straight from xh/xl [M][K];
// B-fragment straight from WhT/WlT [N][K] (L2-resident).  128x256 block,
// 4 waves 2Mx2N, wave = 64x128 = 4mi x 8ni frags of 16x16x32.
// OOB rows clamped to M-1 for loads (dummy math, epilogue guards stores).
// ---------------------------------------------------------------------------
__global__ __launch_bounds__(256, 2) void k_gemm1d(
    const _Float16* __restrict__ Ah, const _Float16* __restrict__ Al,
    const _Float16* __restrict__ BhT, const _Float16* __restrict__ BlT,
    _Float16* __restrict__ C, int M, int N, int K) {
  const int tid = threadIdx.x;
  const int bm = blockIdx.x * 128;
  const int wave = tid >> 6, lane = tid & 63;
  const int wm = (wave & 1) * 64, wn = (wave >> 1) * 128;
  const int lr = lane & 15, quad = lane >> 4;

  const _Float16 *a0[4], *l0[4];
#pragma unroll
  for (int mi = 0; mi < 4; ++mi) {
    int row = bm + wm + mi * 16 + lr;
    row = row < M ? row : M - 1;
    a0[mi] = Ah + (size_t)row * K + quad * 8;
    l0[mi] = Al + (size_t)row * K + quad * 8;
  }
  const _Float16* bh0 = BhT + (size_t)(wn + lr) * K + quad * 8;
  const _Float16* bl0 = BlT + (size_t)(wn + lr) * K + quad * 8;

  f32x4 acc[4][8] = {};
  for (int k0 = 0; k0 < K; k0 += 32) {
    half8v af[4], alf[4];
#pragma unroll
    for (int mi = 0; mi < 4; ++mi) {
      af[mi] = *(const half8v*)(a0[mi] + k0);
      alf[mi] = *(const half8v*)(l0[mi] + k0);
    }
#pragma unroll
    for (int ni = 0; ni < 8; ++ni) {
      half8v bh = *(const half8v*)(bh0 + (size_t)(ni * 16) * K + k0);
      half8v bl = *(const half8v*)(bl0 + (size_t)(ni * 16) * K + k0);
#pragma unroll
      for (int mi = 0; mi < 4; ++mi) {
        acc[mi][ni] = __builtin_amdgcn_mfma_f32_16x16x32_f16(
            af[mi], bh, acc[mi][ni], 0, 0, 0);
        acc[mi][ni] = __builtin_amdgcn_mfma_f32_16x16x32_f16(
            af[mi], bl, acc[mi][ni], 0, 0, 0);
        acc[mi][ni] = __builtin_amdgcn_mfma_f32_16x16x32_f16(
            alf[mi], bh, acc[mi][ni], 0, 0, 0);
      }
    }
  }

  // epilogue: C/D frag col=lane&15, row=quad*4+r
#pragma unroll
  for (int mi = 0; mi < 4; ++mi)
#pragma unroll
    for (int r = 0; r < 4; ++r) {
      int row = bm + wm + mi * 16 + quad * 4 + r;
      if (row < M) {
#pragma unroll
        for (int ni = 0; ni < 8; ++ni)
          C[(size_t)row * N + wn + ni * 16 + lr] = (_Float16)acc[mi][ni][r];
      }
    }
}

// ---------------------------------------------------------------------------
// 9. k_gemm2d: h2[M,128] = fp16(h1r @ W2), 2-term split-B, DIRECT fragments.
// 128x128 block, 4 waves 2Mx2N, wave = 64x64 = 4mi x 4ni frags.
// ---------------------------------------------------------------------------
__global__ __launch_bounds__(256, 2) void k_gemm2d(
    const _Float16* __restrict__ A, const _Float16* __restrict__ BhT,
    const _Float16* __restrict__ BlT, _Float16* __restrict__ C,
    int M, int N, int K) {
  const int tid = threadIdx.x;
  const int bm = blockIdx.x * 128;
  const int wave = tid >> 6, lane = tid & 63;
  const int wm = (wave & 1) * 64, wn = (wave >> 1) * 64;
  const int lr = lane & 15, quad = lane >> 4;

  const _Float16* a0[4];
#pragma unroll
  for (int mi = 0; mi < 4; ++mi) {
    int row = bm + wm + mi * 16 + lr;
    row = row < M ? row : M - 1;
    a0[mi] = A + (size_t)row * K + quad * 8;
  }
  const _Float16* bh0 = BhT + (size_t)(wn + lr) * K + quad * 8;
  const _Float16* bl0 = BlT + (size_t)(wn + lr) * K + quad * 8;

  f32x4 acc[4][4] = {};
  for (int k0 = 0; k0 < K; k0 += 32) {
    half8v af[4];
#pragma unroll
    for (int mi = 0; mi < 4; ++mi) af[mi] = *(const half8v*)(a0[mi] + k0);
#pragma unroll
    for (int ni = 0; ni < 4; ++ni) {
      half8v bh = *(const half8v*)(bh0 + (size_t)(ni * 16) * K + k0);
      half8v bl = *(const half8v*)(bl0 + (size_t)(ni * 16) * K + k0);
#pragma unroll
      for (int mi = 0; mi < 4; ++mi) {
        acc[mi][ni] = __builtin_amdgcn_mfma_f32_16x16x32_f16(
            af[mi], bh, acc[mi][ni], 0, 0, 0);
        acc[mi][ni] = __builtin_amdgcn_mfma_f32_16x16x32_f16(
            af[mi], bl, acc[mi][ni], 0, 0, 0);
      }
    }
  }

#pragma unroll
  for (int mi = 0; mi < 4; ++mi)
#pragma unroll
    for (int r = 0; r < 4; ++r) {
      int row = bm + wm + mi * 16 + quad * 4 + r;
      if (row < M) {
#pragma unroll
        for (int ni = 0; ni < 4; ++ni)
          C[(size_t)row * N + wn + ni * 16 + lr] = (_Float16)acc[mi][ni][r];
      }
    }
}

// ---------------------------------------------------------------------------
// 8/10. Streaming aggregation (R4 version, the 342us practical floor).
//   LPE = C/8 lanes cover one row (each lane 8 ch = 16 B dwordx4 load)
//   EPL = 64/LPE edge rows gathered per wave-load; U=4 unrolled groups
// out = di * ( di*h[i] + sum_e dinv[src]*h[src] ) + bias  [; relu]
// ---------------------------------------------------------------------------
template <int C, bool RELU, typename OutT>
__global__ __launch_bounds__(256) void k_agg(const _Float16* __restrict__ h,
                                             const int* __restrict__ esrc,
                                             const int* __restrict__ off,
                                             const float* __restrict__ dinv,
                                             const float* __restrict__ bias,
                                             OutT* __restrict__ out, int n) {
  constexpr int LPE = C / 8;     // lanes per edge row
  constexpr int EPL = 64 / LPE;  // edge rows per wave-load
  constexpr int U = 4;           // unrolled groups
  int gwave = (blockIdx.x * 256 + threadIdx.x) >> 6;
  int lane = threadIdx.x & 63;
  if (gwave >= n) return;
  const int i = gwave;
  const int eslot = lane / LPE;
  const int sub = lane % LPE;
  const float di = dinv[i];
  const _Float16* hb = h + sub * 8;

  f32x8 acc = {};
  if (eslot == 0)
    acc = di * __builtin_convertvector(*(const half8v*)(hb + (size_t)i * C),
                                       f32x8);

  int e = off[i];
  const int e1 = off[i + 1];
  for (; e + U * EPL <= e1; e += U * EPL) {
    int s[U];
#pragma unroll
    for (int g = 0; g < U; ++g) s[g] = esrc[e + g * EPL + eslot];
    float w[U];
    half8v v[U];
#pragma unroll
    for (int g = 0; g < U; ++g) {
      w[g] = dinv[s[g]];
      v[g] = *(const half8v*)(hb + (size_t)s[g] * C);
    }
#pragma unroll
    for (int g = 0; g < U; ++g)
      acc += w[g] * __builtin_convertvector(v[g], f32x8);
  }
  for (; e < e1; e += EPL) {
    int eg = e + eslot;
    if (eg < e1) {
      int s = esrc[eg];
      acc += dinv[s] * __builtin_convertvector(
                           *(const half8v*)(hb + (size_t)s * C), f32x8);
    }
  }

  // combine edge-slot partials (butterfly over slot strides)
#pragma unroll
  for (int j = 0; j < 8; ++j) {
    float t = acc[j];
#pragma unroll
    for (int m = LPE; m < 64; m <<= 1) t += __shfl_xor(t, m);
    acc[j] = t;
  }

  if (eslot == 0) {
    f32x8 bv = *(const f32x8*)(bias + sub * 8);
    f32x8 r = acc * di + bv;
    if (RELU) {
#pragma unroll
      for (int j = 0; j < 8; ++j) r[j] = fmaxf(r[j], 0.f);
    }
    if constexpr (sizeof(OutT) == 2) {
      *(half8v*)(out + (size_t)i * C + sub * 8) =
          __builtin_convertvector(r, half8v);
    } else {
      *(f32x8*)(out + (size_t)i * C + sub * 8) = r;
    }
  }
}

// ---------------------------------------------------------------------------
extern "C" void kernel_launch(void* const* d_in, const int* in_sizes, int n_in,
                              void* d_out, int out_size, void* d_ws, size_t ws_size,
                              hipStream_t stream) {
  const float* x  = (const float*)d_in[0];
  const int*   ei = (const int*)d_in[1];
  const float* W1 = (const float*)d_in[2];
  const float* b1 = (const float*)d_in[3];
  const float* W2 = (const float*)d_in[4];
  const float* b2 = (const float*)d_in[5];
  float* out = (float*)d_out;

  const int IN_CH = 256, HID = 256, OUT = 128;
  const int N = in_sizes[0] / IN_CH;   // 100000
  const int E = in_sizes[1] / 2;       // 3200000
  const int* src = ei;
  const int* dst = ei + E;
  const int NB = (N + NPB - 1) / NPB;  // 391 buckets

  // workspace layout.  Aliases (stream-ordered lifetimes):
  //   xh = h1r slab (xh dead before agg1 writes h1r)
  //   xl = sliceA slab, shared with tmp (tmp dead after k_bucket)
  char* p = (char*)d_ws;
  auto alloc = [&](size_t bytes) {
    void* r = (void*)p;
    p += (bytes + 255) & ~(size_t)255;
    return r;
  };
  _Float16* h1   = (_Float16*)alloc((size_t)N * HID * 2);  // reused as h2
  _Float16* h1r  = (_Float16*)alloc((size_t)N * HID * 2);
  int*      esrc = (int*)alloc((size_t)E * 4);
  int*      off  = (int*)alloc((size_t)(N + 1) * 4);
  float*    dinv = (float*)alloc((size_t)N * 4);
  int*      bcnt = (int*)alloc((size_t)(NB + 1) * 4);
  int*      bbase= (int*)alloc((size_t)(NB + 1) * 4);
  int*      gcur = (int*)alloc((size_t)(NB + 1) * 4);
  _Float16* w1h  = (_Float16*)alloc((size_t)IN_CH * HID * 2);
  _Float16* w1l  = (_Float16*)alloc((size_t)IN_CH * HID * 2);
  _Float16* w2h  = (_Float16*)alloc((size_t)HID * OUT * 2);
  _Float16* w2l  = (_Float16*)alloc((size_t)HID * OUT * 2);
  size_t sliceBytes = (size_t)E * 8;                       // tmp: 25.6MB
  size_t xlBytes = (size_t)N * IN_CH * 2;                  // xl:  51.2MB
  char*  sliceA = (char*)alloc(sliceBytes > xlBytes ? sliceBytes : xlBytes);
  if ((size_t)(p - (char*)d_ws) > ws_size) {
    fprintf(stderr, "kernel_launch: ws too small (need %zu, have %zu)\n",
            (size_t)(p - (char*)d_ws), ws_size);
    return;
  }
  uint2*    tmp = (uint2*)sliceA;
  _Float16* xl  = (_Float16*)sliceA;   // valid after k_bucket
  _Float16* xh  = h1r;                 // valid until agg1

  const int nBlkP = (E + PCHUNK - 1) / PCHUNK;  // 391

  // 1-2. bucket histogram + scan
  hipMemsetAsync(bcnt, 0, (size_t)(NB + 1) * 4, stream);
  k_bhist<<<nBlkP, 256, 0, stream>>>(dst, bcnt, E, NB);
  k_bscan<<<1, 512, 0, stream>>>(bcnt, bbase, gcur, NB);
  // 3. partition into buckets
  k_partition<<<nBlkP, 256, 0, stream>>>(src, dst, gcur, tmp, E, NB);
  // 4. per-bucket sort -> esrc, off, dinv
  k_bucket<<<NB, 256, 0, stream>>>(tmp, bbase, off, dinv, esrc, N);
  // 5. W splits (transposed)
  k_castWT<<<(IN_CH * HID + 255) / 256, 256, 0, stream>>>(W1, w1h, w1l, IN_CH, HID);
  k_castWT<<<(HID * OUT + 255) / 256, 256, 0, stream>>>(W2, w2h, w2l, HID, OUT);
  // 6. x split (tmp is dead now; xl overlays it)
  k_castX<<<(N * IN_CH / 4 + 255) / 256, 256, 0, stream>>>(
      x, xh, xl, N * IN_CH / 4);
  // 7. h1 = fp16(x @ W1): barrier-free direct-fragment GEMM
  k_gemm1d<<<(N + 127) / 128, 256, 0, stream>>>(xh, xl, w1h, w1l, h1,
                                                N, HID, IN_CH);
  // 8. agg layer 1 (+bias, relu) -> h1r fp16 (overwrites xh, now dead)
  int aggBlk = (N + 3) / 4;  // 4 waves per block, wave per node
  k_agg<256, true, _Float16><<<aggBlk, 256, 0, stream>>>(h1, esrc, off, dinv, b1, h1r, N);
  // 9. h2 = fp16(h1r @ W2): direct-fragment GEMM (writes into h1 buffer)
  k_gemm2d<<<(N + 127) / 128, 256, 0, stream>>>(h1r, w2h, w2l, h1, N, OUT, HID);
  // 10. agg layer 2 (+bias) -> out fp32
  k_agg<128, false, float><<<aggBlk, 256, 0, stream>>>(h1, esrc, off, dinv, b2, out, N);
}